// Round 6
// baseline (11.293 us; speedup 1.0000x reference)
//
#include <hip/hip_runtime.h>

// ChannelSimLoss1D, single-dispatch, 32-block x 1-wave version.
// Closed form per sample: ||rowNormGram(x)-rowNormGram(y)||_F^2
//   = nnz(x) + nnz(y) - 2 * (sum_i sign(x_i)sign(y_i)) * cos(x,y)
// out = mean_b / C.  B=32, C=2048, fp32.
// Block == one wave64: no LDS, no __syncthreads. Each lane loads 8 float4
// per array (16 loads in flight), 5-chain wave shuffle reduce.
// Finish: atomicInc(counter,31) cycles mod 32 -> exactly one block sees
// old==30 per call for ANY initial counter value (0xAA poison or steady-state
// 31), deterministic under graph replay with no re-poisoning.

constexpr int B = 32;
constexpr int C = 2048;

__global__ __launch_bounds__(64) void csl_wave(const float* __restrict__ x,
                                               const float* __restrict__ y,
                                               float* __restrict__ partials,
                                               unsigned* __restrict__ counter,
                                               float* __restrict__ out) {
    const int lane = threadIdx.x;       // 0..63
    const int b    = blockIdx.x;        // sample

    const float4* x4 = reinterpret_cast<const float4*>(x + (size_t)b * C);
    const float4* y4 = reinterpret_cast<const float4*>(y + (size_t)b * C);

    // issue all 16 loads back-to-back (compile-time indices -> registers)
    float4 xa0 = x4[lane +   0], xa1 = x4[lane +  64], xa2 = x4[lane + 128], xa3 = x4[lane + 192];
    float4 xa4 = x4[lane + 256], xa5 = x4[lane + 320], xa6 = x4[lane + 384], xa7 = x4[lane + 448];
    float4 ya0 = y4[lane +   0], ya1 = y4[lane +  64], ya2 = y4[lane + 128], ya3 = y4[lane + 192];
    float4 ya4 = y4[lane + 256], ya5 = y4[lane + 320], ya6 = y4[lane + 384], ya7 = y4[lane + 448];

    float sx2 = 0.f, sy2 = 0.f, sxy = 0.f, sp = 0.f, cnt = 0.f;
    auto accum4 = [&](const float4& a, const float4& c4) {
        const float av[4] = {a.x, a.y, a.z, a.w};
        const float bv[4] = {c4.x, c4.y, c4.z, c4.w};
        #pragma unroll
        for (int k = 0; k < 4; ++k) {
            const float u = av[k], v = bv[k];
            sx2 = fmaf(u, u, sx2);
            sy2 = fmaf(v, v, sy2);
            sxy = fmaf(u, v, sxy);
            const float su = (u > 0.f) ? 1.f : ((u < 0.f) ? -1.f : 0.f);
            const float sv = (v > 0.f) ? 1.f : ((v < 0.f) ? -1.f : 0.f);
            sp  = fmaf(su, sv, sp);
            // nnz(x)+nnz(y) combined (only the sum matters); sign(0)=0
            // reproduces the reference's EPS branch exactly.
            cnt += ((u != 0.f) ? 1.f : 0.f) + ((v != 0.f) ? 1.f : 0.f);
        }
    };
    accum4(xa0, ya0); accum4(xa1, ya1); accum4(xa2, ya2); accum4(xa3, ya3);
    accum4(xa4, ya4); accum4(xa5, ya5); accum4(xa6, ya6); accum4(xa7, ya7);

    // 5-chain wave64 shuffle reduce (block == wave: this is the full reduction)
    #pragma unroll
    for (int off = 32; off >= 1; off >>= 1) {
        sx2 += __shfl_down(sx2, off);
        sy2 += __shfl_down(sy2, off);
        sxy += __shfl_down(sxy, off);
        sp  += __shfl_down(sp,  off);
        cnt += __shfl_down(cnt, off);
    }

    unsigned old = 0u;
    if (lane == 0) {
        const float denom = fmaxf(sqrtf(sx2) * sqrtf(sy2), 1e-24f);
        const float val = cnt - 2.f * sp * (sxy / denom);
        __hip_atomic_store(&partials[b], val, __ATOMIC_RELAXED, __HIP_MEMORY_SCOPE_AGENT);
        __threadfence();
        old = atomicInc(counter, B - 1u);   // cycles 0..31
    }
    old = __shfl(old, 0);                   // broadcast; no barrier needed
    if (old == B - 2u) {                    // unique 32nd arriver (any init value)
        __threadfence();
        float v = (lane < B)
            ? __hip_atomic_load(&partials[lane], __ATOMIC_RELAXED, __HIP_MEMORY_SCOPE_AGENT)
            : 0.f;
        #pragma unroll
        for (int off = 32; off >= 1; off >>= 1) v += __shfl_down(v, off);
        if (lane == 0) out[0] = v * (1.f / (float)(B * C));
    }
}

extern "C" void kernel_launch(void* const* d_in, const int* in_sizes, int n_in,
                              void* d_out, int out_size, void* d_ws, size_t ws_size,
                              hipStream_t stream) {
    const float* x = (const float*)d_in[0];
    const float* y = (const float*)d_in[1];
    float* partials = (float*)d_ws;                      // 32 floats
    unsigned* counter = (unsigned*)((char*)d_ws + 256);  // own cache line
    csl_wave<<<B, 64, 0, stream>>>(x, y, partials, counter, (float*)d_out);
}

// Round 7
// 9.652 us; speedup vs baseline: 1.1700x; 1.1700x over previous
//
#include <hip/hip_runtime.h>

// ChannelSimLoss1D — FINAL: single-dispatch, 32 blocks x 256 threads (the
// measured optimum of the R2..R6 structural sweep; 9.56 us).
// Closed form per sample: ||rowNormGram(x)-rowNormGram(y)||_F^2
//   = nnz(x) + nnz(y) - 2 * (sum_i sign(x_i)sign(y_i)) * cos(x,y)
// out = mean_b / C.  B=32, C=2048, fp32.
// One block per sample, 4 waves, 2 float4/lane/array; 5-chain shuffle reduce
// (nnz(x)+nnz(y) merged since only the sum is needed); LDS combine; finish via
// atomicInc(counter,31): cycles mod 32 so exactly one block observes old==30
// per call for ANY initial counter value (0xAA poison on first replay,
// steady-state 31 after) -> deterministic under graph replay, no re-poison.

constexpr int B = 32;
constexpr int C = 2048;
constexpr int THREADS = 256;

__global__ __launch_bounds__(THREADS) void csl_fused(const float* __restrict__ x,
                                                     const float* __restrict__ y,
                                                     float* __restrict__ partials,
                                                     unsigned* __restrict__ counter,
                                                     float* __restrict__ out) {
    const int b = blockIdx.x;
    const int tid = threadIdx.x;
    const int wave = tid >> 6;
    const float4* x4 = reinterpret_cast<const float4*>(x + (size_t)b * C);
    const float4* y4 = reinterpret_cast<const float4*>(y + (size_t)b * C);

    // two float4 per array per thread, fully coalesced, all 4 loads in flight
    const float4 a0 = x4[tid];
    const float4 a1 = x4[tid + THREADS];
    const float4 b0 = y4[tid];
    const float4 b1 = y4[tid + THREADS];

    float sx2 = 0.f, sy2 = 0.f, sxy = 0.f, sp = 0.f, cnt = 0.f;
    auto accum4 = [&](const float4& a, const float4& c4) {
        const float av[4] = {a.x, a.y, a.z, a.w};
        const float bv[4] = {c4.x, c4.y, c4.z, c4.w};
        #pragma unroll
        for (int k = 0; k < 4; ++k) {
            const float u = av[k], v = bv[k];
            sx2 = fmaf(u, u, sx2);
            sy2 = fmaf(v, v, sy2);
            sxy = fmaf(u, v, sxy);
            const float su = (u > 0.f) ? 1.f : ((u < 0.f) ? -1.f : 0.f);
            const float sv = (v > 0.f) ? 1.f : ((v < 0.f) ? -1.f : 0.f);
            sp = fmaf(su, sv, sp);
            // nnz(x)+nnz(y) merged (only the sum enters the result);
            // sign(0)=0 reproduces the reference's EPS branch exactly.
            cnt += ((u != 0.f) ? 1.f : 0.f) + ((v != 0.f) ? 1.f : 0.f);
        }
    };
    accum4(a0, b0);
    accum4(a1, b1);

    // 5-chain wave64 shuffle reduce
    #pragma unroll
    for (int off = 32; off >= 1; off >>= 1) {
        sx2 += __shfl_down(sx2, off);
        sy2 += __shfl_down(sy2, off);
        sxy += __shfl_down(sxy, off);
        sp  += __shfl_down(sp,  off);
        cnt += __shfl_down(cnt, off);
    }

    __shared__ float red[THREADS / 64][5];
    __shared__ bool amLast;
    if ((tid & 63) == 0) {
        red[wave][0] = sx2; red[wave][1] = sy2; red[wave][2] = sxy;
        red[wave][3] = sp;  red[wave][4] = cnt;
    }
    __syncthreads();

    if (tid == 0) {
        float t0 = 0.f, t1 = 0.f, t2 = 0.f, t3 = 0.f, t4 = 0.f;
        #pragma unroll
        for (int w = 0; w < THREADS / 64; ++w) {
            t0 += red[w][0]; t1 += red[w][1]; t2 += red[w][2];
            t3 += red[w][3]; t4 += red[w][4];
        }
        const float denom = fmaxf(sqrtf(t0) * sqrtf(t1), 1e-24f);
        const float val = t4 - 2.f * t3 * (t2 / denom);

        __hip_atomic_store(&partials[b], val, __ATOMIC_RELAXED, __HIP_MEMORY_SCOPE_AGENT);
        __threadfence();
        const unsigned old = atomicInc(counter, B - 1u);  // cycles 0..31
        amLast = (old == B - 2u);                         // unique 32nd arriver
    }
    __syncthreads();

    if (amLast && tid < 64) {
        __threadfence();
        float v = (tid < B)
            ? __hip_atomic_load(&partials[tid], __ATOMIC_RELAXED, __HIP_MEMORY_SCOPE_AGENT)
            : 0.f;
        #pragma unroll
        for (int off = 32; off >= 1; off >>= 1) v += __shfl_down(v, off);
        if (tid == 0) out[0] = v * (1.f / (float)(B * C));
    }
}

extern "C" void kernel_launch(void* const* d_in, const int* in_sizes, int n_in,
                              void* d_out, int out_size, void* d_ws, size_t ws_size,
                              hipStream_t stream) {
    const float* x = (const float*)d_in[0];
    const float* y = (const float*)d_in[1];
    float* partials = (float*)d_ws;                      // 32 floats
    unsigned* counter = (unsigned*)((char*)d_ws + 256);  // own cache line
    csl_fused<<<B, THREADS, 0, stream>>>(x, y, partials, counter, (float*)d_out);
}